// Round 5
// baseline (24.284 us; speedup 1.0000x reference)
//
#include <hip/hip_runtime.h>
#include <math.h>

#define HWp 65536   // 256*256

__global__ __launch_bounds__(128)
void gp_encoder_kernel(const float* __restrict__ x,
                       const float* __restrict__ Wt,
                       const float* __restrict__ be,
                       float* __restrict__ out)
{
    // R exchange buffer: [entry][pixel-lane], stride-1 per entry -> conflict-free
    __shared__ float Rsh[36][64];

    const int lane = threadIdx.x & 63;
    const int wid  = threadIdx.x >> 6;      // 0 = wave A (R builder), 1 = wave B (S / y)

    // --- ALL of these are block-uniform (scalar): blocks are 64-aligned in one row ---
    const int blk  = blockIdx.x;            // 4096 blocks, 64 px each
    const int b    = blk >> 10;             // 1024 blocks per batch image
    const int pixb = (blk & 1023) << 6;     // base pixel within image
    const int h    = pixb >> 8;
    const int w0   = pixb & 255;            // 0, 64, 128, 192

    // lane-edge predicates (only lanes at the true image edge are masked)
    const bool wlo_ok = !(w0 == 0   && lane == 0);
    const bool whi_ok = !(w0 == 192 && lane == 63);
    const int  idx_m1 = wlo_ok ? lane - 1 : lane;   // clamped (safe) address
    const int  idx_p1 = whi_ok ? lane + 1 : lane;

    // ---------------- 3x3x3 neighborhood: scalar row bases + lane voffset ----------
    float xv[27];
    const float* xb = x + b * 3 * HWp;      // scalar
    #pragma unroll
    for (int ci = 0; ci < 3; ++ci) {
        #pragma unroll
        for (int kh = 0; kh < 3; ++kh) {
            const int hh = h + kh - 1;      // scalar
            float v0 = 0.f, v1 = 0.f, v2 = 0.f;
            if ((unsigned)hh < 256u) {      // uniform branch
                const float* rp = xb + ci * HWp + hh * 256 + w0;  // scalar base
                v0 = rp[idx_m1];
                v1 = rp[lane];
                v2 = rp[idx_p1];
                v0 = wlo_ok ? v0 : 0.f;
                v2 = whi_ok ? v2 : 0.f;
            }
            xv[ci*9 + kh*3 + 0] = v0;
            xv[ci*9 + kh*3 + 1] = v1;
            xv[ci*9 + kh*3 + 2] = v2;
        }
    }

    // scalar output-plane bases
    float* out_xf = out                 + b*3*HWp  + pixb;
    float* out_m  = out + 4*3*HWp       + b*6*HWp  + pixb;
    float* out_S  = out + (4*3+4*6)*HWp + b*36*HWp + pixb;
    float* out_y  = out + (4*3+4*6+4*36)*HWp + b*3*HWp + pixb;

    // persists across the barrier in wave-B registers
    float pb[15];   // pb[0..5]=m, pb[6..11]=s, pb[12..14]=xf
    float d6[6];

    if (wid == 0) {
        // ---------------- wave A: angle channels 12..26 -> R ----------------
        float pa[15];
        #pragma unroll
        for (int o = 0; o < 15; ++o) {
            const int ch = 12 + o;
            float acc = be[ch];
            #pragma unroll
            for (int t = 0; t < 27; ++t)
                acc = fmaf(xv[t], Wt[ch*27 + t], acc);
            pa[o] = acc;
        }

        // all 15 (cos,sin): ang = 2*pi*sigmoid(t); v_sin/v_cos take revolutions
        float cs[15], ss[15];
        #pragma unroll
        for (int k = 0; k < 15; ++k) {
            const float e  = __expf(-pa[k]);
            const float sg = __builtin_amdgcn_rcpf(1.f + e);
            cs[k] = __builtin_amdgcn_cosf(sg);
            ss[k] = __builtin_amdgcn_sinf(sg);
        }

        // R = I * G0 * ... * G14 (column ops)
        float R[6][6];
        #pragma unroll
        for (int r = 0; r < 6; ++r)
            #pragma unroll
            for (int c = 0; c < 6; ++c)
                R[r][c] = (r == c) ? 1.f : 0.f;

        const int PI_[15] = {0,0,0,0,0,1,1,1,1,2,2,2,3,3,4};
        const int PJ_[15] = {1,2,3,4,5,2,3,4,5,3,4,5,4,5,5};
        #pragma unroll
        for (int k = 0; k < 15; ++k) {
            const int i = PI_[k], j = PJ_[k];
            const float c = cs[k], sn = ss[k];
            #pragma unroll
            for (int r = 0; r < 6; ++r) {
                const float ri = R[r][i], rj = R[r][j];
                R[r][i] = c * ri + sn * rj;
                R[r][j] = c * rj - sn * ri;
            }
        }

        // publish R (vaddr = lane*4, imm offsets)
        #pragma unroll
        for (int e = 0; e < 36; ++e)
            Rsh[e][lane] = R[e / 6][e % 6];
    } else {
        // ---------------- wave B: channels 0..11, 27..29 ----------------
        #pragma unroll
        for (int o = 0; o < 15; ++o) {
            const int ch = (o < 12) ? o : (o + 15);
            float acc = be[ch];
            #pragma unroll
            for (int t = 0; t < 27; ++t)
                acc = fmaf(xv[t], Wt[ch*27 + t], acc);
            pb[o] = acc;
        }

        // write m (ch 0..5) and xf (ch 27..29): scalar base + lane
        #pragma unroll
        for (int c = 0; c < 6; ++c)
            out_m[c*HWp + lane] = pb[c];
        #pragma unroll
        for (int i = 0; i < 3; ++i)
            out_xf[i*HWp + lane] = pb[12 + i];

        // d = clip(s^2, 1e-6)   (relu(s)-relu(-s) == s)
        #pragma unroll
        for (int k = 0; k < 6; ++k) {
            const float s = pb[6 + k];
            d6[k] = fmaxf(s * s, 1e-6f);
        }
    }

    __syncthreads();

    if (wid == 0) return;   // wave A retires

    // ---------------- wave B: S = R diag(d) R^T, Q, y ----------------
    float R[6][6];
    #pragma unroll
    for (int e = 0; e < 36; ++e)
        R[e / 6][e % 6] = Rsh[e][lane];

    float syxf[3][3], syyf[3][3];
    #pragma unroll
    for (int m = 0; m < 6; ++m) {
        float rdm[6];
        #pragma unroll
        for (int k = 0; k < 6; ++k)
            rdm[k] = R[m][k] * d6[k];
        #pragma unroll
        for (int n = m; n < 6; ++n) {
            float acc = 0.f;
            #pragma unroll
            for (int k = 0; k < 6; ++k)
                acc = fmaf(rdm[k], R[n][k], acc);
            out_S[(m*6 + n)*HWp + lane] = acc;
            if (n != m)
                out_S[(n*6 + m)*HWp + lane] = acc;
            if (m < 3) { if (n >= 3) syxf[n-3][m] = acc; }
            else       { syyf[m-3][n-3] = acc; if (n != m) syyf[n-3][m-3] = acc; }
        }
    }

    // Q = -S_yy^{-1} S_yx  (exact identity; f64 inverse of well-scaled block)
    const double a00 = (double)syyf[0][0], a01 = (double)syyf[0][1], a02 = (double)syyf[0][2];
    const double a10 = (double)syyf[1][0], a11 = (double)syyf[1][1], a12 = (double)syyf[1][2];
    const double a20 = (double)syyf[2][0], a21 = (double)syyf[2][1], a22 = (double)syyf[2][2];

    const double det = a00*(a11*a22 - a12*a21)
                     - a01*(a10*a22 - a12*a20)
                     + a02*(a10*a21 - a11*a20);
    const double idet = 1.0 / det;

    double inv[3][3];
    inv[0][0] =  (a11*a22 - a12*a21) * idet;
    inv[0][1] = -(a01*a22 - a02*a21) * idet;
    inv[0][2] =  (a01*a12 - a02*a11) * idet;
    inv[1][0] = -(a10*a22 - a12*a20) * idet;
    inv[1][1] =  (a00*a22 - a02*a20) * idet;
    inv[1][2] = -(a00*a12 - a02*a10) * idet;
    inv[2][0] =  (a10*a21 - a11*a20) * idet;
    inv[2][1] = -(a00*a21 - a01*a20) * idet;
    inv[2][2] =  (a00*a11 - a01*a10) * idet;

    double Qp[3][3];
    #pragma unroll
    for (int r = 0; r < 3; ++r)
        #pragma unroll
        for (int c = 0; c < 3; ++c) {
            double acc = 0.0;
            #pragma unroll
            for (int k = 0; k < 3; ++k)
                acc = fma(inv[r][k], (double)syxf[k][c], acc);
            Qp[r][c] = acc;
        }

    // y = my - Qp (xf - mx);  mx = pb[0..2], my = pb[3..5], xf = pb[12..14]
    #pragma unroll
    for (int i = 0; i < 3; ++i) {
        double acc = (double)pb[3 + i];
        #pragma unroll
        for (int n = 0; n < 3; ++n)
            acc = fma(-Qp[i][n], (double)pb[12 + n] - (double)pb[n], acc);
        out_y[i*HWp + lane] = (float)acc;
    }
}

extern "C" void kernel_launch(void* const* d_in, const int* in_sizes, int n_in,
                              void* d_out, int out_size, void* d_ws, size_t ws_size,
                              hipStream_t stream) {
    const float* x  = (const float*)d_in[0];
    const float* Wt = (const float*)d_in[1];
    const float* be = (const float*)d_in[2];
    float* out = (float*)d_out;

    dim3 grid(4096);   // 262144 pixels / 64 per block
    dim3 block(128);   // 2 waves: A (R builder) + B (S / y)
    hipLaunchKernelGGL(gp_encoder_kernel, grid, block, 0, stream, x, Wt, be, out);
}

// Round 6
// 23.943 us; speedup vs baseline: 1.0142x; 1.0142x over previous
//
#include <hip/hip_runtime.h>
#include <math.h>

#define HWp 65536   // 256*256

typedef float v2f __attribute__((ext_vector_type(2)));

__device__ __forceinline__ v2f fma2(v2f a, v2f b, v2f c) {
    return __builtin_elementwise_fma(a, b, c);   // -> v_pk_fma_f32
}

__global__ __launch_bounds__(128)
void gp_encoder_kernel(const float* __restrict__ x,
                       const float* __restrict__ Wt,
                       const float* __restrict__ be,
                       float* __restrict__ out)
{
    // R exchange: [lane][entry], 38-dword row stride (8B-aligned, gcd(38,32)=2 -> free)
    __shared__ float Rsh[64][38];

    const int lane = threadIdx.x & 63;
    const int wid  = threadIdx.x >> 6;      // 0 = wave A (R builder), 1 = wave B (S / y)

    // block-uniform coordinates (blocks are 64-aligned within one image row)
    const int blk  = blockIdx.x;
    const int b    = blk >> 10;
    const int pixb = (blk & 1023) << 6;
    const int h    = pixb >> 8;
    const int w0   = pixb & 255;

    const bool wlo_ok = !(w0 == 0   && lane == 0);
    const bool whi_ok = !(w0 == 192 && lane == 63);
    const int  idx_m1 = wlo_ok ? lane - 1 : lane;
    const int  idx_p1 = whi_ok ? lane + 1 : lane;

    // ---------------- 3x3x3 neighborhood ----------------
    float xs[27];
    const float* xb = x + b * 3 * HWp;
    #pragma unroll
    for (int ci = 0; ci < 3; ++ci) {
        #pragma unroll
        for (int kh = 0; kh < 3; ++kh) {
            const int hh = h + kh - 1;      // scalar
            float v0 = 0.f, v1 = 0.f, v2 = 0.f;
            if ((unsigned)hh < 256u) {      // uniform branch
                const float* rp = xb + ci * HWp + hh * 256 + w0;
                v0 = rp[idx_m1];
                v1 = rp[lane];
                v2 = rp[idx_p1];
                v0 = wlo_ok ? v0 : 0.f;
                v2 = whi_ok ? v2 : 0.f;
            }
            xs[ci*9 + kh*3 + 0] = v0;
            xs[ci*9 + kh*3 + 1] = v1;
            xs[ci*9 + kh*3 + 2] = v2;
        }
    }
    // tap pairs (static indices -> stays in registers)
    v2f xp[13];
    #pragma unroll
    for (int q = 0; q < 13; ++q)
        xp[q] = (v2f){xs[2*q], xs[2*q + 1]};
    const float x26 = xs[26];

    // scalar output-plane bases
    float* out_xf = out                      + b*3*HWp  + pixb;
    float* out_m  = out + 4*3*HWp            + b*6*HWp  + pixb;
    float* out_S  = out + (4*3+4*6)*HWp      + b*36*HWp + pixb;
    float* out_y  = out + (4*3+4*6+4*36)*HWp + b*3*HWp  + pixb;

    float pb[15];   // wave B: [0..5]=m, [6..11]=s, [12..14]=xf
    v2f   d2[3];    // wave B: variance pairs

    if (wid == 0) {
        // ---------------- wave A: angle channels 12..26 -> R ----------------
        float pa[15];
        #pragma unroll
        for (int o = 0; o < 15; ++o) {
            const int base = (12 + o) * 27;
            v2f acc2 = (v2f){0.f, 0.f};
            #pragma unroll
            for (int q = 0; q < 13; ++q) {
                v2f wq;
                wq.x = Wt[base + 2*q];
                wq.y = Wt[base + 2*q + 1];   // adjacent s_loads -> s_load_dwordx2
                acc2 = fma2(xp[q], wq, acc2);
            }
            const float r = be[12 + o] + acc2.x + acc2.y;
            pa[o] = fmaf(x26, Wt[base + 26], r);
        }

        // (cos,sin) of 2*pi*sigmoid(t): v_sin/v_cos take revolutions
        float cs[15], ss[15];
        #pragma unroll
        for (int k = 0; k < 15; ++k) {
            const float e  = __expf(-pa[k]);
            const float sg = __builtin_amdgcn_rcpf(1.f + e);
            cs[k] = __builtin_amdgcn_cosf(sg);
            ss[k] = __builtin_amdgcn_sinf(sg);
        }

        // R as column-major row-pairs: Rc[col][rowpair]
        v2f Rc[6][3];
        #pragma unroll
        for (int c = 0; c < 6; ++c)
            #pragma unroll
            for (int p = 0; p < 3; ++p)
                Rc[c][p] = (v2f){(2*p == c) ? 1.f : 0.f, (2*p + 1 == c) ? 1.f : 0.f};

        const int PI_[15] = {0,0,0,0,0,1,1,1,1,2,2,2,3,3,4};
        const int PJ_[15] = {1,2,3,4,5,2,3,4,5,3,4,5,4,5,5};
        #pragma unroll
        for (int k = 0; k < 15; ++k) {
            const int i = PI_[k], j = PJ_[k];
            const v2f c2 = (v2f){cs[k], cs[k]};
            const v2f s2 = (v2f){ss[k], ss[k]};
            #pragma unroll
            for (int p = 0; p < 3; ++p) {
                const v2f ri = Rc[i][p], rj = Rc[j][p];
                Rc[i][p] = fma2(c2, ri, s2 * rj);        // c*ri + s*rj
                Rc[j][p] = fma2(c2, rj, -(s2 * ri));     // c*rj - s*ri
            }
        }

        // publish R row-major: Rsh[lane][m*6+k] = R[m][k]
        #pragma unroll
        for (int m = 0; m < 6; ++m)
            #pragma unroll
            for (int k = 0; k < 6; ++k)
                Rsh[lane][m*6 + k] = (m & 1) ? Rc[k][m >> 1].y : Rc[k][m >> 1].x;
    } else {
        // ---------------- wave B: channels 0..11, 27..29 ----------------
        #pragma unroll
        for (int o = 0; o < 15; ++o) {
            const int ch   = (o < 12) ? o : (o + 15);
            const int base = ch * 27;
            v2f acc2 = (v2f){0.f, 0.f};
            #pragma unroll
            for (int q = 0; q < 13; ++q) {
                v2f wq;
                wq.x = Wt[base + 2*q];
                wq.y = Wt[base + 2*q + 1];
                acc2 = fma2(xp[q], wq, acc2);
            }
            const float r = be[ch] + acc2.x + acc2.y;
            pb[o] = fmaf(x26, Wt[base + 26], r);
        }

        // write m (ch 0..5) and xf (ch 27..29)
        #pragma unroll
        for (int c = 0; c < 6; ++c)
            out_m[c*HWp + lane] = pb[c];
        #pragma unroll
        for (int i = 0; i < 3; ++i)
            out_xf[i*HWp + lane] = pb[12 + i];

        // d = clip(s^2, 1e-6) as pairs
        #pragma unroll
        for (int p = 0; p < 3; ++p) {
            const v2f s = (v2f){pb[6 + 2*p], pb[7 + 2*p]};
            d2[p] = __builtin_elementwise_max(s * s, (v2f){1e-6f, 1e-6f});
        }
    }

    __syncthreads();

    if (wid == 0) return;   // wave A retires

    // ---------------- wave B: S = R diag(d) R^T, Q, y ----------------
    // row-major k-pairs via ds_read_b64 (8B-aligned: 38*4*lane + even*4)
    v2f R2[6][3];
    #pragma unroll
    for (int m = 0; m < 6; ++m)
        #pragma unroll
        for (int p = 0; p < 3; ++p)
            R2[m][p] = *reinterpret_cast<const v2f*>(&Rsh[lane][m*6 + 2*p]);

    float syxf[3][3], syyf[3][3];
    #pragma unroll
    for (int m = 0; m < 6; ++m) {
        v2f rdm[3];
        #pragma unroll
        for (int p = 0; p < 3; ++p)
            rdm[p] = R2[m][p] * d2[p];
        #pragma unroll
        for (int n = m; n < 6; ++n) {
            v2f a2 = rdm[0] * R2[n][0];
            a2 = fma2(rdm[1], R2[n][1], a2);
            a2 = fma2(rdm[2], R2[n][2], a2);
            const float acc = a2.x + a2.y;
            out_S[(m*6 + n)*HWp + lane] = acc;
            if (n != m)
                out_S[(n*6 + m)*HWp + lane] = acc;
            if (m < 3) { if (n >= 3) syxf[n-3][m] = acc; }
            else       { syyf[m-3][n-3] = acc; if (n != m) syyf[n-3][m-3] = acc; }
        }
    }

    // Q = -S_yy^{-1} S_yx  (exact identity; f64 inverse of well-scaled block)
    const double a00 = (double)syyf[0][0], a01 = (double)syyf[0][1], a02 = (double)syyf[0][2];
    const double a10 = (double)syyf[1][0], a11 = (double)syyf[1][1], a12 = (double)syyf[1][2];
    const double a20 = (double)syyf[2][0], a21 = (double)syyf[2][1], a22 = (double)syyf[2][2];

    const double det = a00*(a11*a22 - a12*a21)
                     - a01*(a10*a22 - a12*a20)
                     + a02*(a10*a21 - a11*a20);
    const double idet = 1.0 / det;

    double inv[3][3];
    inv[0][0] =  (a11*a22 - a12*a21) * idet;
    inv[0][1] = -(a01*a22 - a02*a21) * idet;
    inv[0][2] =  (a01*a12 - a02*a11) * idet;
    inv[1][0] = -(a10*a22 - a12*a20) * idet;
    inv[1][1] =  (a00*a22 - a02*a20) * idet;
    inv[1][2] = -(a00*a12 - a02*a10) * idet;
    inv[2][0] =  (a10*a21 - a11*a20) * idet;
    inv[2][1] = -(a00*a21 - a01*a20) * idet;
    inv[2][2] =  (a00*a11 - a01*a10) * idet;

    double Qp[3][3];
    #pragma unroll
    for (int r = 0; r < 3; ++r)
        #pragma unroll
        for (int c = 0; c < 3; ++c) {
            double acc = 0.0;
            #pragma unroll
            for (int k = 0; k < 3; ++k)
                acc = fma(inv[r][k], (double)syxf[k][c], acc);
            Qp[r][c] = acc;
        }

    // y = my - Qp (xf - mx)
    #pragma unroll
    for (int i = 0; i < 3; ++i) {
        double acc = (double)pb[3 + i];
        #pragma unroll
        for (int n = 0; n < 3; ++n)
            acc = fma(-Qp[i][n], (double)pb[12 + n] - (double)pb[n], acc);
        out_y[i*HWp + lane] = (float)acc;
    }
}

extern "C" void kernel_launch(void* const* d_in, const int* in_sizes, int n_in,
                              void* d_out, int out_size, void* d_ws, size_t ws_size,
                              hipStream_t stream) {
    const float* x  = (const float*)d_in[0];
    const float* Wt = (const float*)d_in[1];
    const float* be = (const float*)d_in[2];
    float* out = (float*)d_out;

    dim3 grid(4096);   // 262144 pixels / 64 per block
    dim3 block(128);   // 2 waves: A (R builder) + B (S / y)
    hipLaunchKernelGGL(gp_encoder_kernel, grid, block, 0, stream, x, Wt, be, out);
}